// Round 19
// baseline (124.762 us; speedup 1.0000x reference)
//
#include <hip/hip_runtime.h>
#include <hip/hip_bf16.h>
#include <stdint.h>

typedef unsigned short u16;
typedef __attribute__((ext_vector_type(8))) __bf16 bf16x8;
typedef __attribute__((ext_vector_type(2))) __bf16 bf16x2;
typedef __attribute__((ext_vector_type(4))) float f32x4;
typedef __attribute__((ext_vector_type(4))) u16 u16x4;
typedef __attribute__((ext_vector_type(4))) float f32x4v;

typedef __attribute__((address_space(1))) void gvoid_t;
typedef __attribute__((address_space(3))) void lvoid_t;

#define BAR()     asm volatile("s_barrier" ::: "memory")
#define WAITV0()  asm volatile("s_waitcnt vmcnt(0)" ::: "memory")
#define WAITV2()  asm volatile("s_waitcnt vmcnt(2)" ::: "memory")
#define WAITV4()  asm volatile("s_waitcnt vmcnt(4)" ::: "memory")
#define WAITV6()  asm volatile("s_waitcnt vmcnt(6)" ::: "memory")
#define WAITV8()  asm volatile("s_waitcnt vmcnt(8)" ::: "memory")
#define WAITV12() asm volatile("s_waitcnt vmcnt(12)" ::: "memory")
#define WAITLGKM0() asm volatile("s_waitcnt lgkmcnt(0)" ::: "memory")

__device__ inline u16 f2bf(float f) {
    uint32_t u = __float_as_uint(f);
    u += 0x7fff + ((u >> 16) & 1);   // RNE
    return (u16)(u >> 16);
}

__device__ inline float bf2f(u16 v) {
    return __uint_as_float(((uint32_t)v) << 16);
}

__device__ inline void gll16(const void* g, void* l) {
    __builtin_amdgcn_global_load_lds((gvoid_t*)g, (lvoid_t*)l, 16, 0, 0);
}

__device__ inline f32x4 mfma16(bf16x8 a, bf16x8 b, f32x4 c) {
    return __builtin_amdgcn_mfma_f32_16x16x32_bf16(a, b, c, 0, 0, 0);
}

// V slot permutation: context row r (mod 64) -> storage slot, so that the PV
// A-fragment is IN-LANE after swapped QK^T (keys n*16+g*4+j live in lane g).
__device__ inline int vslot(int r) {
    int n = r >> 4;
    return ((n >> 1) << 5) + (((r >> 2) & 3) << 3) + ((n & 1) << 2) + (r & 3);
}

// ---------------- prep: queries cast (blocks 0..2047) + W transposes (2048..6143)
// context cast ELIMINATED: the KV GEMM now reads context fp32 directly and
// casts during reg-staging (saves 48MB of HBM traffic in this kernel).
__global__ __launch_bounds__(256) void prep_kernel(
        const float* __restrict__ q, const float* __restrict__ Wq,
        const float* __restrict__ Wkv, const float* __restrict__ Wo,
        u16* __restrict__ qb, u16* __restrict__ WqT,
        u16* __restrict__ WkvT, u16* __restrict__ WoT) {
    const int bid = blockIdx.x;
    const int tid = threadIdx.x;
    if (bid < 2048) {
        int i = bid * 256 + tid;            // 524288 f32x4 groups of queries
        f32x4v f = ((const f32x4v*)q)[i];
        u16x4 o;
        o[0] = f2bf(f[0]); o[1] = f2bf(f[1]); o[2] = f2bf(f[2]); o[3] = f2bf(f[3]);
        ((u16x4*)qb)[i] = o;
        return;
    }
    int b2 = bid - 2048;
    const float* W; u16* WT; int N, n0, k0;
    if (b2 < 1024)      { W = Wq;  WT = WqT;  N = 1024; n0 = (b2 & 31) * 32; k0 = (b2 >> 5) * 32; }
    else if (b2 < 3072) { int b3 = b2 - 1024; W = Wkv; WT = WkvT; N = 2048; n0 = (b3 & 63) * 32; k0 = (b3 >> 6) * 32; }
    else                { int b3 = b2 - 3072; W = Wo;  WT = WoT;  N = 1024; n0 = (b3 & 31) * 32; k0 = (b3 >> 5) * 32; }
    __shared__ float t[32][33];
    int x = tid & 31, y = tid >> 5;
    for (int yy = y; yy < 32; yy += 8)
        t[yy][x] = W[(size_t)(k0 + yy) * N + n0 + x];
    __syncthreads();
    for (int yy = y; yy < 32; yy += 8)
        WT[(size_t)(n0 + yy) * 1024 + k0 + x] = f2bf(t[x][yy]);
}

// ---------------- small GEMM: 64x128 tile, 8 waves, 4-slot counted ring ---------
// (R12-proven; used standalone for the O projection, MODE 2)
template <int MODE>
__global__ __launch_bounds__(512, 2) void gemm_bt(
        const u16* __restrict__ A, const u16* __restrict__ Bt,
        const float* __restrict__ bias, int M, int N, int K,
        float scale, void* __restrict__ out0) {
    __shared__ u16 lds[4][6144];          // [slot][A: 64*32 | B at +2048: 128*32]
    const int NT = K >> 5;                // K/32
    const int tid = threadIdx.x;          // 0..511
    const int lane = tid & 63, wv = tid >> 6;   // wv 0..7
    const int c16 = lane & 15, g = lane >> 4;
    const int m0 = blockIdx.y * 64, n0 = blockIdx.x * 128;

    const int idxA = (wv & 3) * 64 + lane;
    const int rA = idxA >> 2, ccA = (idxA & 3) ^ ((rA >> 1) & 3);
    const size_t offA = (size_t)(m0 + rA) * K + ccA * 8;
    const int dstA = (wv & 3) * 512;
    const int idxB = wv * 64 + lane;
    const int rB = idxB >> 2, ccB = (idxB & 3) ^ ((rB >> 1) & 3);
    const size_t offB = (size_t)(n0 + rB) * K + ccB * 8;
    const int dstB = 2048 + wv * 512;

    auto stage = [&](int t) {
        gll16(A + offA + t * 32, &lds[t & 3][dstA]);
        gll16(Bt + offB + t * 32, &lds[t & 3][dstB]);
    };

    const int wm = (wv >> 1) * 16, wn = (wv & 1) * 64;
    f32x4 acc[4] = {};

    auto compute = [&](int slot) {
        const u16* la = &lds[slot][0];
        const u16* lb = &lds[slot][2048];
        int rowa = wm + c16;
        bf16x8 af = *(const bf16x8*)&la[rowa * 32 + (g ^ ((rowa >> 1) & 3)) * 8];
        bf16x8 bfr[4];
#pragma unroll
        for (int n = 0; n < 4; n++) {
            int row = wn + n * 16 + c16;
            bfr[n] = *(const bf16x8*)&lb[row * 32 + (g ^ ((row >> 1) & 3)) * 8];
        }
        __builtin_amdgcn_s_setprio(1);
#pragma unroll
        for (int n = 0; n < 4; n++)
            acc[n] = mfma16(af, bfr[n], acc[n]);
        __builtin_amdgcn_s_setprio(0);
    };

    stage(0); stage(1); stage(2);        // 6 loads/thread in flight

    for (int t = 0; t < NT - 2; ++t) {
        WAITV4();
        BAR();
        if (t + 3 < NT) stage(t + 3);
        compute(t & 3);
    }
    WAITV2(); BAR(); compute((NT - 2) & 3);
    WAITV0(); BAR(); compute((NT - 1) & 3);

#pragma unroll
    for (int n = 0; n < 4; n++) {
        int col = n0 + wn + n * 16 + c16;
        float bv = bias[col];
        int rowb = m0 + wm + g * 4;
#pragma unroll
        for (int j = 0; j < 4; j++) {
            float v = (acc[n][j] + bv) * scale;
            int row = rowb + j;
            if (MODE == 0) {
                ((u16*)out0)[(size_t)row * N + col] = f2bf(v);
            } else {
                ((float*)out0)[(size_t)row * N + col] = v;
            }
        }
    }
}

// ---------------- fused QKV projection dispatch --------------------------------
// Blocks 0..255: KV GEMM 256x256, 4-slot counted ring. A (context) is read as
// FP32 and cast during reg-staging (T14 order: loadA(t+3) issued BEFORE
// writeA(t+2) so the compiler's auto-vmcnt is counted, not a drain); B (WkvT)
// stays global_load_lds. Per-tile vmem group/thread = [4 A-loads, 2 B-gll16]
// -> steady WAITV12, tail 6 -> 0; ds_writes flushed by lgkmcnt(0) before BAR.
// Blocks 256..511: Q projection (R12-proven 64x128 gll16 ring), 49KB LDS view.
__global__ __launch_bounds__(512, 2) void fused_qkv(
        const float* __restrict__ ctx, const u16* __restrict__ WkvT,
        const float* __restrict__ bkv, u16* __restrict__ Kp,
        u16* __restrict__ VpT,
        const u16* __restrict__ qb, const u16* __restrict__ WqT,
        const float* __restrict__ bq, float qscale, u16* __restrict__ Qp) {
    __shared__ u16 smem[4][2][8192];      // 131072 B
    const int tid = threadIdx.x;
    const int lane = tid & 63, wv = tid >> 6;
    const int c16 = lane & 15, g = lane >> 4;
    const int bidg = blockIdx.x;

    if (bidg < 256) {
        // ---- KV path: C[8192][2048] = ctx(bf16-cast) @ WkvT^T + bkv ----
        const int K = 1024, NT = 32;
        const int cpx = 32;
        const int sw = (bidg & 7) * cpx + (bidg >> 3);
        const int bx = sw & 7, by = sw >> 3;
        const int m0 = by * 256, n0 = bx * 256;

        // A: 1024 chunks (256 rows x 4 swz-chunks); thread covers tid, tid+512
        const int rA0 = tid >> 2,         chA0 = (tid & 3) ^ ((rA0 >> 1) & 3);
        const int rA1 = (tid + 512) >> 2, chA1 = (tid & 3) ^ ((rA1 >> 1) & 3);
        const size_t offA0 = (size_t)(m0 + rA0) * K + chA0 * 8;
        const size_t offA1 = (size_t)(m0 + rA1) * K + chA1 * 8;
        const int dA0 = tid * 8, dA1 = (tid + 512) * 8;   // elem offsets (A region)
        // B: 1024 chunks; thread covers 2 via gll16 (wave-uniform dest)
        size_t offB[2]; int dstB[2];
#pragma unroll
        for (int j = 0; j < 2; j++) {
            int cch = j * 512 + wv * 64 + lane;
            int r = cch >> 2, ch = (cch & 3) ^ ((r >> 1) & 3);
            offB[j] = (size_t)(n0 + r) * K + ch * 8;
            dstB[j] = (j * 512 + wv * 64) * 8;
        }

        f32x4v raE[4], raO[4];
        auto loadA = [&](int t, f32x4v* ra) {
            ra[0] = *(const f32x4v*)(ctx + offA0 + (size_t)t * 32);
            ra[1] = *(const f32x4v*)(ctx + offA0 + (size_t)t * 32 + 4);
            ra[2] = *(const f32x4v*)(ctx + offA1 + (size_t)t * 32);
            ra[3] = *(const f32x4v*)(ctx + offA1 + (size_t)t * 32 + 4);
        };
        auto writeA = [&](int t, const f32x4v* ra) {
            u16* d = &smem[t & 3][0][0];
            union { u16 s[8]; bf16x8 v; } p0, p1;
#pragma unroll
            for (int j = 0; j < 4; j++) {
                p0.s[j] = f2bf(ra[0][j]); p0.s[4 + j] = f2bf(ra[1][j]);
                p1.s[j] = f2bf(ra[2][j]); p1.s[4 + j] = f2bf(ra[3][j]);
            }
            *(bf16x8*)(d + dA0) = p0.v;
            *(bf16x8*)(d + dA1) = p1.v;
        };
        auto stageB = [&](int t) {
#pragma unroll
            for (int j = 0; j < 2; j++)
                gll16(WkvT + offB[j] + (size_t)t * 32, &smem[t & 3][1][0] + dstB[j]);
        };

        const int wm = wv >> 2;
        const int wn = wv & 3;
        f32x4 acc[8][4] = {};

        auto compute = [&](int slot) {
            const u16* la = &smem[slot][0][0];
            const u16* lb = &smem[slot][1][0];
            bf16x8 af[8], bfr[4];
#pragma unroll
            for (int m = 0; m < 8; m++) {
                int row = wm * 128 + m * 16 + c16;
                af[m] = *(const bf16x8*)&la[row * 32 + (g ^ ((row >> 1) & 3)) * 8];
            }
#pragma unroll
            for (int n = 0; n < 4; n++) {
                int row = wn * 64 + n * 16 + c16;
                bfr[n] = *(const bf16x8*)&lb[row * 32 + (g ^ ((row >> 1) & 3)) * 8];
            }
            __builtin_amdgcn_s_setprio(1);
#pragma unroll
            for (int m = 0; m < 8; m++)
#pragma unroll
                for (int n = 0; n < 4; n++)
                    acc[m][n] = mfma16(af[m], bfr[n], acc[m][n]);
            __builtin_amdgcn_s_setprio(0);
        };

        // prologue: [lA(0),sB(0)][lA(1),sB(1)][w(0)][lA(2),sB(2)][w(1)]
        loadA(0, raE); stageB(0);
        loadA(1, raO); stageB(1);
        writeA(0, raE);
        loadA(2, raE); stageB(2);
        writeA(1, raO);

        for (int t = 0; t < NT; ++t) {
            if (t < NT - 2) { WAITV12(); } else if (t == NT - 2) { WAITV6(); } else { WAITV0(); }
            WAITLGKM0();
            BAR();
            if (t & 1) {
                if (t + 3 < NT) loadA(t + 3, raE);
                if (t + 2 < NT) writeA(t + 2, raO);
            } else {
                if (t + 3 < NT) loadA(t + 3, raO);
                if (t + 2 < NT) writeA(t + 2, raE);
            }
            if (t + 3 < NT) stageB(t + 3);
            compute(t & 3);
        }

        const bool isV = (n0 >= 1024);
#pragma unroll
        for (int n = 0; n < 4; n++) {
            int col = n0 + wn * 64 + n * 16 + c16;
            float bv = bkv[col];
#pragma unroll
            for (int m = 0; m < 8; m++) {
                int rowb = m0 + wm * 128 + m * 16 + g * 4;
                if (isV) {
                    u16x4 pk;
#pragma unroll
                    for (int j = 0; j < 4; j++) pk[j] = f2bf(acc[m][n][j] + bv);
                    int vcol = (rowb & ~63) + vslot(rowb & 63);
                    *(u16x4*)&VpT[(size_t)(col - 1024) * 8192 + vcol] = pk;
                } else {
#pragma unroll
                    for (int j = 0; j < 4; j++)
                        Kp[(size_t)(rowb + j) * 1024 + col] = f2bf(acc[m][n][j] + bv);
                }
            }
        }
    } else {
        // ---- Q path: Qp[2048][1024] = (qb @ WqT^T + bq) * qscale, bf16 ----
        const int K = 1024, N = 1024, NT = 32;
        const int b2 = bidg - 256;
        const int m0 = (b2 >> 3) * 64, n0 = (b2 & 7) * 128;
        u16* base = &smem[0][0][0];       // Q path uses first 24576 u16 (49KB)

        const int idxA = (wv & 3) * 64 + lane;
        const int rA = idxA >> 2, ccA = (idxA & 3) ^ ((rA >> 1) & 3);
        const size_t offA = (size_t)(m0 + rA) * K + ccA * 8;
        const int dstA = (wv & 3) * 512;
        const int idxB = wv * 64 + lane;
        const int rB = idxB >> 2, ccB = (idxB & 3) ^ ((rB >> 1) & 3);
        const size_t offB = (size_t)(n0 + rB) * K + ccB * 8;
        const int dstB = 2048 + wv * 512;

        auto stage = [&](int t) {
            u16* d = base + (t & 3) * 6144;
            gll16(qb + offA + t * 32, d + dstA);
            gll16(WqT + offB + t * 32, d + dstB);
        };

        const int wm = (wv >> 1) * 16, wn = (wv & 1) * 64;
        f32x4 acc[4] = {};

        auto compute = [&](int slot) {
            const u16* la = base + slot * 6144;
            const u16* lb = la + 2048;
            int rowa = wm + c16;
            bf16x8 af = *(const bf16x8*)&la[rowa * 32 + (g ^ ((rowa >> 1) & 3)) * 8];
            bf16x8 bfr[4];
#pragma unroll
            for (int n = 0; n < 4; n++) {
                int row = wn + n * 16 + c16;
                bfr[n] = *(const bf16x8*)&lb[row * 32 + (g ^ ((row >> 1) & 3)) * 8];
            }
            __builtin_amdgcn_s_setprio(1);
#pragma unroll
            for (int n = 0; n < 4; n++)
                acc[n] = mfma16(af, bfr[n], acc[n]);
            __builtin_amdgcn_s_setprio(0);
        };

        stage(0); stage(1); stage(2);

        for (int t = 0; t < NT - 2; ++t) {
            WAITV4();
            BAR();
            if (t + 3 < NT) stage(t + 3);
            compute(t & 3);
        }
        WAITV2(); BAR(); compute((NT - 2) & 3);
        WAITV0(); BAR(); compute((NT - 1) & 3);

#pragma unroll
        for (int n = 0; n < 4; n++) {
            int col = n0 + wn + n * 16 + c16;
            float bv = bq[col];
            int rowb = m0 + wm + g * 4;
#pragma unroll
            for (int j = 0; j < 4; j++) {
                float v = (acc[n][j] + bv) * qscale;
                Qp[(size_t)(rowb + j) * N + col] = f2bf(v);
            }
        }
    }
}

// ---------------- flash attention: QBLK=128, 4 waves x 2 q-sets, kv-split x2 ----
// grid 512 (1-D): qblk(2b) in HIGH bits -> KV-sharing blocks group per XCD.
// 16 kv tiles of 64 keys; 3-slot counted-vmcnt ring; LDS 48KB. T5 setprio.
__global__ __launch_bounds__(256, 3) void attn_split_kernel(
        const u16* __restrict__ Qp, const u16* __restrict__ Kp,
        const u16* __restrict__ VpT, u16* __restrict__ Opart,
        float* __restrict__ ml) {
    __shared__ u16 lKV[3][2][64 * 64];   // [slot][K=0/V=1] = 49152 B
    const int NT = 16;
    const int tid = threadIdx.x;
    const int lane = tid & 63, wv = tid >> 6;      // wv 0..3
    const int c16 = lane & 15, g = lane >> 4;
    const int bid = blockIdx.x;
    const int qblk = bid >> 7;            // 0..3, high bits (XCD slab grouping)
    const int low = bid & 127;
    const int h = low & 15, z = low >> 4;  // z 0..7
    const int b = z >> 1, sp = z & 1;
    const int kvbase = sp * 1024;

    bf16x8 qf[2][2];
#pragma unroll
    for (int qs = 0; qs < 2; qs++) {
        int qrow = b * 512 + qblk * 128 + qs * 64 + wv * 16 + c16;
        qf[qs][0] = *(const bf16x8*)(Qp + (size_t)qrow * 1024 + h * 64 + g * 8);
        qf[qs][1] = *(const bf16x8*)(Qp + (size_t)qrow * 1024 + h * 64 + 32 + g * 8);
    }

    f32x4 acc[2][4] = {};
    float m_s[2] = {-1e30f, -1e30f}, l_s[2] = {0.f, 0.f};   // log2 domain

    const int r0 = tid >> 3, c0 = (tid & 7) ^ (r0 & 7);
    const int r1 = 32 + r0,  c1 = (tid & 7) ^ (r1 & 7);
    const int dst0 = wv * 512, dst1 = 2048 + wv * 512;   // u16 offsets

    auto stageKV = [&](int t) {
        int slot = t % 3;
        int kv0 = kvbase + t * 64;
        u16* dK = &lKV[slot][0][0];
        u16* dV = &lKV[slot][1][0];
        gll16(Kp + (size_t)(b * 2048 + kv0 + r0) * 1024 + h * 64 + c0 * 8, dK + dst0);
        gll16(Kp + (size_t)(b * 2048 + kv0 + r1) * 1024 + h * 64 + c1 * 8, dK + dst1);
        gll16(VpT + (size_t)(h * 64 + r0) * 8192 + b * 2048 + kv0 + c0 * 8, dV + dst0);
        gll16(VpT + (size_t)(h * 64 + r1) * 8192 + b * 2048 + kv0 + c1 * 8, dV + dst1);
    };

    stageKV(0); stageKV(1);
    for (int t = 0; t < NT; ++t) {
        if (t < NT - 1) { WAITV4(); } else { WAITV0(); }
        BAR();
        if (t + 2 < NT) stageKV(t + 2);

        const int slot = t % 3;
        const u16* lK = &lKV[slot][0][0];
        const u16* lV = &lKV[slot][1][0];

        f32x4 s[2][4];
#pragma unroll
        for (int n = 0; n < 4; n++) {
            s[0][n] = f32x4{0.f, 0.f, 0.f, 0.f};
            s[1][n] = f32x4{0.f, 0.f, 0.f, 0.f};
        }
        __builtin_amdgcn_s_setprio(1);
#pragma unroll
        for (int n = 0; n < 4; n++) {
            int key = n * 16 + c16;
#pragma unroll
            for (int kk = 0; kk < 2; kk++) {
                bf16x8 kf = *(const bf16x8*)&lK[key * 64 + (((kk * 4 + g) ^ (key & 7))) * 8];
                s[0][n] = mfma16(kf, qf[0][kk], s[0][n]);
                s[1][n] = mfma16(kf, qf[1][kk], s[1][n]);
            }
        }
        __builtin_amdgcn_s_setprio(0);

        uint32_t r[2][4][2];
#pragma unroll
        for (int qs = 0; qs < 2; qs++) {
            float mn0 = fmaxf(fmaxf(s[qs][0][0], s[qs][0][1]), fmaxf(s[qs][0][2], s[qs][0][3]));
            float mn1 = fmaxf(fmaxf(s[qs][1][0], s[qs][1][1]), fmaxf(s[qs][1][2], s[qs][1][3]));
            float mn2 = fmaxf(fmaxf(s[qs][2][0], s[qs][2][1]), fmaxf(s[qs][2][2], s[qs][2][3]));
            float mn3 = fmaxf(fmaxf(s[qs][3][0], s[qs][3][1]), fmaxf(s[qs][3][2], s[qs][3][3]));
            float mx = fmaxf(fmaxf(mn0, mn1), fmaxf(mn2, mn3));
            mx = fmaxf(mx, __shfl_xor(mx, 16));
            mx = fmaxf(mx, __shfl_xor(mx, 32));

            if (!__all(mx - m_s[qs] <= 8.0f)) {
                float mn = fmaxf(m_s[qs], mx);
                float al = exp2f(m_s[qs] - mn);
                m_s[qs] = mn;
                l_s[qs] *= al;
                float alr[4];
#pragma unroll
                for (int j = 0; j < 4; j++) alr[j] = __shfl(al, g * 4 + j);
#pragma unroll
                for (int nd = 0; nd < 4; nd++)
#pragma unroll
                    for (int j = 0; j < 4; j++) acc[qs][nd][j] *= alr[j];
            }

            float sums[4];
#pragma unroll
            for (int n = 0; n < 4; n++) {
                float p0 = exp2f(s[qs][n][0] - m_s[qs]);
                float p1 = exp2f(s[qs][n][1] - m_s[qs]);
                float p2 = exp2f(s[qs][n][2] - m_s[qs]);
                float p3 = exp2f(s[qs][n][3] - m_s[qs]);
                sums[n] = (p0 + p1) + (p2 + p3);
                union { bf16x2 h; uint32_t u; } ca, cb;
                ca.h[0] = (__bf16)p0; ca.h[1] = (__bf16)p1;
                cb.h[0] = (__bf16)p2; cb.h[1] = (__bf16)p3;
                r[qs][n][0] = ca.u; r[qs][n][1] = cb.u;
            }
            float sum = (sums[0] + sums[1]) + (sums[2] + sums[3]);
            sum += __shfl_xor(sum, 16);
            sum += __shfl_xor(sum, 32);
            l_s[qs] += sum;
        }

        __builtin_amdgcn_s_setprio(1);
#pragma unroll
        for (int kk2 = 0; kk2 < 2; kk2++) {
            union { bf16x8 v8; uint32_t u[4]; } pa0, pa1;
            pa0.u[0] = r[0][kk2 * 2][0];     pa0.u[1] = r[0][kk2 * 2][1];
            pa0.u[2] = r[0][kk2 * 2 + 1][0]; pa0.u[3] = r[0][kk2 * 2 + 1][1];
            pa1.u[0] = r[1][kk2 * 2][0];     pa1.u[1] = r[1][kk2 * 2][1];
            pa1.u[2] = r[1][kk2 * 2 + 1][0]; pa1.u[3] = r[1][kk2 * 2 + 1][1];
#pragma unroll
            for (int nd = 0; nd < 4; nd++) {
                int d = nd * 16 + c16;
                bf16x8 vf = *(const bf16x8*)&lV[d * 64 + (((kk2 * 4 + g) ^ (d & 7))) * 8];
                acc[0][nd] = mfma16(pa0.v8, vf, acc[0][nd]);
                acc[1][nd] = mfma16(pa1.v8, vf, acc[1][nd]);
            }
        }
        __builtin_amdgcn_s_setprio(0);
    }

#pragma unroll
    for (int qs = 0; qs < 2; qs++) {
#pragma unroll
        for (int j = 0; j < 4; j++) {
            int rowq = b * 512 + qblk * 128 + qs * 64 + wv * 16 + g * 4 + j;
            size_t idx = (size_t)sp * 32768 + (size_t)rowq * 16 + h;
#pragma unroll
            for (int nd = 0; nd < 4; nd++)
                Opart[idx * 64 + nd * 16 + c16] = f2bf(acc[qs][nd][j]);
        }
        if (g == 0) {
            int rowq = b * 512 + qblk * 128 + qs * 64 + wv * 16 + c16;
            size_t idx = (size_t)sp * 32768 + (size_t)rowq * 16 + h;
            ml[idx * 2] = m_s[qs];
            ml[idx * 2 + 1] = l_s[qs];
        }
    }
}

// ---------------- combine the 2 kv-split partials -> X bf16 (log2-domain m) ------
__global__ __launch_bounds__(256) void attn_combine_kernel(
        const u16* __restrict__ Opart, const float* __restrict__ ml,
        u16* __restrict__ X) {
    const int tid = threadIdx.x;
    const int r = blockIdx.x * 4 + (tid >> 6);   // rowhead 0..32767
    const int d = tid & 63;
    float m0 = ml[(size_t)r * 2], l0 = ml[(size_t)r * 2 + 1];
    float m1 = ml[(size_t)(32768 + r) * 2], l1 = ml[(size_t)(32768 + r) * 2 + 1];
    float M = fmaxf(m0, m1);
    float a0 = exp2f(m0 - M), a1 = exp2f(m1 - M);
    float li = 1.f / (l0 * a0 + l1 * a1);
    float o0 = bf2f(Opart[(size_t)r * 64 + d]);
    float o1 = bf2f(Opart[(size_t)(32768 + r) * 64 + d]);
    float o = (o0 * a0 + o1 * a1) * li;
    int qrow = r >> 4, h = r & 15;
    X[(size_t)qrow * 1024 + h * 64 + d] = f2bf(o);
}

// ---------------- launch ----------------
extern "C" void kernel_launch(void* const* d_in, const int* in_sizes, int n_in,
                              void* d_out, int out_size, void* d_ws, size_t ws_size,
                              hipStream_t stream) {
    const float* queries = (const float*)d_in[0];   // [4,512,1024]
    const float* context = (const float*)d_in[1];   // [4,2048,1024]
    const float* Wq      = (const float*)d_in[2];   // [1024,1024]
    const float* bq      = (const float*)d_in[3];   // [1024]
    const float* Wkv     = (const float*)d_in[4];   // [1024,2048]
    const float* bkv     = (const float*)d_in[5];   // [2048]
    const float* Wo      = (const float*)d_in[6];   // [1024,1024]
    const float* bo      = (const float*)d_in[7];   // [1024]

    char* ws = (char*)d_ws;
    u16* qb   = (u16*)(ws);                         // queries bf16   4MB (dead after Q-proj)
    u16* WqT  = (u16*)(ws + (20ull << 20));         // Wq^T bf16      2MB
    u16* WkvT = (u16*)(ws + (22ull << 20));         // Wkv^T bf16     4MB
    u16* WoT  = (u16*)(ws + (26ull << 20));         // Wo^T bf16      2MB
    u16* Qp   = (u16*)(ws + (28ull << 20));         // q proj (x0.125*log2e) 4MB
    u16* Kp   = (u16*)(ws + (32ull << 20));         // k proj        16MB
    u16* VpT  = (u16*)(ws + (48ull << 20));         // v proj ^T (vslot cols) 16MB
    u16* X    = (u16*)(ws + (64ull << 20));         // attn out       4MB
    float* ml    = (float*)qb;                      // 512KB, aliases dead qb
    u16*   Opart = (u16*)(ws + (4ull << 20));       // 8MB bf16 (2 splits)

    prep_kernel<<<dim3(6144), dim3(256), 0, stream>>>(queries, Wq, Wkv, Wo,
                                                      qb, WqT, WkvT, WoT);

    // fused KV GEMM (blocks 0..255, context read as fp32) + Q proj (256..511)
    // Q scale = 1/8 * log2(e): scores computed directly in exp2 domain
    fused_qkv<<<dim3(512), dim3(512), 0, stream>>>(context, WkvT, bkv, Kp, VpT,
                                                   qb, WqT, bq, 0.18033688f, Qp);
    attn_split_kernel<<<dim3(512), dim3(256), 0, stream>>>(Qp, Kp, VpT, Opart, ml);
    attn_combine_kernel<<<dim3(8192), dim3(256), 0, stream>>>(Opart, ml, X);
    gemm_bt<2><<<dim3(8, 32), dim3(512), 0, stream>>>(X, WoT, bo, 2048, 1024, 1024,
                                                      1.0f, d_out);
}

// Round 20
// 117.099 us; speedup vs baseline: 1.0654x; 1.0654x over previous
//
#include <hip/hip_runtime.h>
#include <hip/hip_bf16.h>
#include <stdint.h>

typedef unsigned short u16;
typedef __attribute__((ext_vector_type(8))) __bf16 bf16x8;
typedef __attribute__((ext_vector_type(2))) __bf16 bf16x2;
typedef __attribute__((ext_vector_type(4))) float f32x4;
typedef __attribute__((ext_vector_type(4))) u16 u16x4;
typedef __attribute__((ext_vector_type(4))) float f32x4v;

typedef __attribute__((address_space(1))) void gvoid_t;
typedef __attribute__((address_space(3))) void lvoid_t;

#define BAR()    asm volatile("s_barrier" ::: "memory")
#define WAITV0() asm volatile("s_waitcnt vmcnt(0)" ::: "memory")
#define WAITV2() asm volatile("s_waitcnt vmcnt(2)" ::: "memory")
#define WAITV4() asm volatile("s_waitcnt vmcnt(4)" ::: "memory")
#define WAITV8() asm volatile("s_waitcnt vmcnt(8)" ::: "memory")

__device__ inline u16 f2bf(float f) {
    uint32_t u = __float_as_uint(f);
    u += 0x7fff + ((u >> 16) & 1);   // RNE
    return (u16)(u >> 16);
}

__device__ inline float bf2f(u16 v) {
    return __uint_as_float(((uint32_t)v) << 16);
}

__device__ inline void gll16(const void* g, void* l) {
    __builtin_amdgcn_global_load_lds((gvoid_t*)g, (lvoid_t*)l, 16, 0, 0);
}

__device__ inline f32x4 mfma16(bf16x8 a, bf16x8 b, f32x4 c) {
    return __builtin_amdgcn_mfma_f32_16x16x32_bf16(a, b, c, 0, 0, 0);
}

// V slot permutation: context row r (mod 64) -> storage slot, so that the PV
// A-fragment is IN-LANE after swapped QK^T (keys n*16+g*4+j live in lane g).
__device__ inline int vslot(int r) {
    int n = r >> 4;
    return ((n >> 1) << 5) + (((r >> 2) & 3) << 3) + ((n & 1) << 2) + (r & 3);
}

// ---------------- fused prep: casts (blocks 0..10239) + transposes (10240..14335)
__global__ __launch_bounds__(256) void prep_kernel(
        const float* __restrict__ q, const float* __restrict__ c,
        const float* __restrict__ Wq, const float* __restrict__ Wkv,
        const float* __restrict__ Wo, u16* __restrict__ qb,
        u16* __restrict__ cb, u16* __restrict__ WqT,
        u16* __restrict__ WkvT, u16* __restrict__ WoT) {
    const int bid = blockIdx.x;
    const int tid = threadIdx.x;
    if (bid < 10240) {
        int i = bid * 256 + tid;
        const float* src; u16* dst; int j;
        if (i < 524288) { src = q; dst = qb; j = i; }
        else            { src = c; dst = cb; j = i - 524288; }
        f32x4v f = ((const f32x4v*)src)[j];
        u16x4 o;
        o[0] = f2bf(f[0]); o[1] = f2bf(f[1]); o[2] = f2bf(f[2]); o[3] = f2bf(f[3]);
        ((u16x4*)dst)[j] = o;
        return;
    }
    int b2 = bid - 10240;
    const float* W; u16* WT; int N, n0, k0;
    if (b2 < 1024)      { W = Wq;  WT = WqT;  N = 1024; n0 = (b2 & 31) * 32; k0 = (b2 >> 5) * 32; }
    else if (b2 < 3072) { int b3 = b2 - 1024; W = Wkv; WT = WkvT; N = 2048; n0 = (b3 & 63) * 32; k0 = (b3 >> 6) * 32; }
    else                { int b3 = b2 - 3072; W = Wo;  WT = WoT;  N = 1024; n0 = (b3 & 31) * 32; k0 = (b3 >> 5) * 32; }
    __shared__ float t[32][33];
    int x = tid & 31, y = tid >> 5;
    for (int yy = y; yy < 32; yy += 8)
        t[yy][x] = W[(size_t)(k0 + yy) * N + n0 + x];
    __syncthreads();
    for (int yy = y; yy < 32; yy += 8)
        WT[(size_t)(n0 + yy) * 1024 + k0 + x] = f2bf(t[x][yy]);
}

// ---------------- small GEMM: 64x128 tile, 8 waves, 4-slot counted ring ---------
// (R12-proven; used standalone for the O projection, MODE 2)
template <int MODE>
__global__ __launch_bounds__(512, 2) void gemm_bt(
        const u16* __restrict__ A, const u16* __restrict__ Bt,
        const float* __restrict__ bias, int M, int N, int K,
        float scale, void* __restrict__ out0) {
    __shared__ u16 lds[4][6144];          // [slot][A: 64*32 | B at +2048: 128*32]
    const int NT = K >> 5;                // K/32
    const int tid = threadIdx.x;          // 0..511
    const int lane = tid & 63, wv = tid >> 6;   // wv 0..7
    const int c16 = lane & 15, g = lane >> 4;
    const int m0 = blockIdx.y * 64, n0 = blockIdx.x * 128;

    const int idxA = (wv & 3) * 64 + lane;
    const int rA = idxA >> 2, ccA = (idxA & 3) ^ ((rA >> 1) & 3);
    const size_t offA = (size_t)(m0 + rA) * K + ccA * 8;
    const int dstA = (wv & 3) * 512;
    const int idxB = wv * 64 + lane;
    const int rB = idxB >> 2, ccB = (idxB & 3) ^ ((rB >> 1) & 3);
    const size_t offB = (size_t)(n0 + rB) * K + ccB * 8;
    const int dstB = 2048 + wv * 512;

    auto stage = [&](int t) {
        gll16(A + offA + t * 32, &lds[t & 3][dstA]);
        gll16(Bt + offB + t * 32, &lds[t & 3][dstB]);
    };

    const int wm = (wv >> 1) * 16, wn = (wv & 1) * 64;
    f32x4 acc[4] = {};

    auto compute = [&](int slot) {
        const u16* la = &lds[slot][0];
        const u16* lb = &lds[slot][2048];
        int rowa = wm + c16;
        bf16x8 af = *(const bf16x8*)&la[rowa * 32 + (g ^ ((rowa >> 1) & 3)) * 8];
        bf16x8 bfr[4];
#pragma unroll
        for (int n = 0; n < 4; n++) {
            int row = wn + n * 16 + c16;
            bfr[n] = *(const bf16x8*)&lb[row * 32 + (g ^ ((row >> 1) & 3)) * 8];
        }
#pragma unroll
        for (int n = 0; n < 4; n++)
            acc[n] = mfma16(af, bfr[n], acc[n]);
    };

    stage(0); stage(1); stage(2);        // 6 loads/thread in flight

    for (int t = 0; t < NT - 2; ++t) {
        WAITV4();
        BAR();
        if (t + 3 < NT) stage(t + 3);
        compute(t & 3);
    }
    WAITV2(); BAR(); compute((NT - 2) & 3);
    WAITV0(); BAR(); compute((NT - 1) & 3);

#pragma unroll
    for (int n = 0; n < 4; n++) {
        int col = n0 + wn + n * 16 + c16;
        float bv = bias[col];
        int rowb = m0 + wm + g * 4;
#pragma unroll
        for (int j = 0; j < 4; j++) {
            float v = (acc[n][j] + bv) * scale;
            int row = rowb + j;
            if (MODE == 0) {
                ((u16*)out0)[(size_t)row * N + col] = f2bf(v);
            } else {
                ((float*)out0)[(size_t)row * N + col] = v;
            }
        }
    }
}

// ---------------- fused QKV projection dispatch --------------------------------
// 1-D grid 512, 512 threads. Blocks 0..255: KV GEMM (R6-proven 256x256 4-slot
// counted ring). Blocks 256..511: Q projection (R12-proven 64x128 ring), using a
// 49KB view of the same 128KB static LDS.
__global__ __launch_bounds__(512, 2) void fused_qkv(
        const u16* __restrict__ cb, const u16* __restrict__ WkvT,
        const float* __restrict__ bkv, u16* __restrict__ Kp,
        u16* __restrict__ VpT,
        const u16* __restrict__ qb, const u16* __restrict__ WqT,
        const float* __restrict__ bq, float qscale, u16* __restrict__ Qp) {
    __shared__ u16 smem[4][2][8192];      // 131072 B
    const int tid = threadIdx.x;
    const int lane = tid & 63, wv = tid >> 6;
    const int c16 = lane & 15, g = lane >> 4;
    const int bidg = blockIdx.x;

    if (bidg < 256) {
        // ---- KV path: C[8192][2048] = cb @ WkvT^T + bkv ----
        const int K = 1024, NT = 32;
        const int cpx = 32;
        const int sw = (bidg & 7) * cpx + (bidg >> 3);
        const int bx = sw & 7, by = sw >> 3;
        const int m0 = by * 256, n0 = bx * 256;

        const int isB = wv >> 2;
        const int rbase = (wv & 3) * 64;
        const u16* src = isB ? WkvT : cb;
        const int base0 = isB ? n0 : m0;
        size_t off[4];
        const u16* ldst[4];
#pragma unroll
        for (int i = 0; i < 4; i++) {
            int rl = rbase + i * 16 + (lane >> 2);
            int ch = (lane & 3) ^ ((rl >> 1) & 3);
            off[i] = (size_t)(base0 + rl) * K + ch * 8;
            ldst[i] = &smem[0][0][0] + ((size_t)isB * 256 * 32) + (size_t)(rbase + i * 16) * 32;
        }
        const size_t slotStride = 2 * 256 * 32;

        auto stage = [&](int t) {
            const u16* s0 = src + (size_t)t * 32;
            u16* d = (u16*)ldst[0] + (size_t)(t & 3) * slotStride;
            gll16(s0 + off[0], d);
            gll16(s0 + off[1], d + 16 * 32);
            gll16(s0 + off[2], d + 32 * 32);
            gll16(s0 + off[3], d + 48 * 32);
        };

        const int wm = wv >> 2;
        const int wn = wv & 3;
        f32x4 acc[8][4] = {};

        auto compute = [&](int slot) {
            const u16* la = &smem[slot][0][0];
            const u16* lb = &smem[slot][1][0];
            bf16x8 af[8], bfr[4];
#pragma unroll
            for (int m = 0; m < 8; m++) {
                int row = wm * 128 + m * 16 + c16;
                af[m] = *(const bf16x8*)&la[row * 32 + (g ^ ((row >> 1) & 3)) * 8];
            }
#pragma unroll
            for (int n = 0; n < 4; n++) {
                int row = wn * 64 + n * 16 + c16;
                bfr[n] = *(const bf16x8*)&lb[row * 32 + (g ^ ((row >> 1) & 3)) * 8];
            }
#pragma unroll
            for (int m = 0; m < 8; m++)
#pragma unroll
                for (int n = 0; n < 4; n++)
                    acc[m][n] = mfma16(af[m], bfr[n], acc[m][n]);
        };

        stage(0); stage(1); stage(2);

        for (int t = 0; t < NT - 2; ++t) {
            WAITV8();
            BAR();
            if (t + 3 < NT) stage(t + 3);
            compute(t & 3);
        }
        WAITV4(); BAR(); compute((NT - 2) & 3);
        WAITV0(); BAR(); compute((NT - 1) & 3);

        const bool isV = (n0 >= 1024);
#pragma unroll
        for (int n = 0; n < 4; n++) {
            int col = n0 + wn * 64 + n * 16 + c16;
            float bv = bkv[col];
#pragma unroll
            for (int m = 0; m < 8; m++) {
                int rowb = m0 + wm * 128 + m * 16 + g * 4;
                if (isV) {
                    u16x4 pk;
#pragma unroll
                    for (int j = 0; j < 4; j++) pk[j] = f2bf(acc[m][n][j] + bv);
                    int vcol = (rowb & ~63) + vslot(rowb & 63);
                    *(u16x4*)&VpT[(size_t)(col - 1024) * 8192 + vcol] = pk;
                } else {
#pragma unroll
                    for (int j = 0; j < 4; j++)
                        Kp[(size_t)(rowb + j) * 1024 + col] = f2bf(acc[m][n][j] + bv);
                }
            }
        }
    } else {
        // ---- Q path: Qp[2048][1024] = (qb @ WqT^T + bq) * qscale, bf16 ----
        const int K = 1024, N = 1024, NT = 32;
        const int b2 = bidg - 256;
        const int m0 = (b2 >> 3) * 64, n0 = (b2 & 7) * 128;
        u16* base = &smem[0][0][0];       // Q path uses first 24576 u16 (49KB)

        const int idxA = (wv & 3) * 64 + lane;
        const int rA = idxA >> 2, ccA = (idxA & 3) ^ ((rA >> 1) & 3);
        const size_t offA = (size_t)(m0 + rA) * K + ccA * 8;
        const int dstA = (wv & 3) * 512;
        const int idxB = wv * 64 + lane;
        const int rB = idxB >> 2, ccB = (idxB & 3) ^ ((rB >> 1) & 3);
        const size_t offB = (size_t)(n0 + rB) * K + ccB * 8;
        const int dstB = 2048 + wv * 512;

        auto stage = [&](int t) {
            u16* d = base + (t & 3) * 6144;
            gll16(qb + offA + t * 32, d + dstA);
            gll16(WqT + offB + t * 32, d + dstB);
        };

        const int wm = (wv >> 1) * 16, wn = (wv & 1) * 64;
        f32x4 acc[4] = {};

        auto compute = [&](int slot) {
            const u16* la = base + slot * 6144;
            const u16* lb = la + 2048;
            int rowa = wm + c16;
            bf16x8 af = *(const bf16x8*)&la[rowa * 32 + (g ^ ((rowa >> 1) & 3)) * 8];
            bf16x8 bfr[4];
#pragma unroll
            for (int n = 0; n < 4; n++) {
                int row = wn + n * 16 + c16;
                bfr[n] = *(const bf16x8*)&lb[row * 32 + (g ^ ((row >> 1) & 3)) * 8];
            }
#pragma unroll
            for (int n = 0; n < 4; n++)
                acc[n] = mfma16(af, bfr[n], acc[n]);
        };

        stage(0); stage(1); stage(2);

        for (int t = 0; t < NT - 2; ++t) {
            WAITV4();
            BAR();
            if (t + 3 < NT) stage(t + 3);
            compute(t & 3);
        }
        WAITV2(); BAR(); compute((NT - 2) & 3);
        WAITV0(); BAR(); compute((NT - 1) & 3);

#pragma unroll
        for (int n = 0; n < 4; n++) {
            int col = n0 + wn + n * 16 + c16;
            float bv = bq[col];
            int rowb = m0 + wm + g * 4;
#pragma unroll
            for (int j = 0; j < 4; j++) {
                float v = (acc[n][j] + bv) * qscale;
                Qp[(size_t)(rowb + j) * N + col] = f2bf(v);
            }
        }
    }
}

// ---------------- flash attention: QBLK=128, 4 waves x 2 q-sets, kv-split x2 ----
// grid 512 (1-D): qblk(2b) in HIGH bits -> KV-sharing blocks group per XCD.
// 16 kv tiles of 64 keys; 3-slot counted-vmcnt ring; LDS 48KB. T5 setprio.
__global__ __launch_bounds__(256, 3) void attn_split_kernel(
        const u16* __restrict__ Qp, const u16* __restrict__ Kp,
        const u16* __restrict__ VpT, u16* __restrict__ Opart,
        float* __restrict__ ml) {
    __shared__ u16 lKV[3][2][64 * 64];   // [slot][K=0/V=1] = 49152 B
    const int NT = 16;
    const int tid = threadIdx.x;
    const int lane = tid & 63, wv = tid >> 6;      // wv 0..3
    const int c16 = lane & 15, g = lane >> 4;
    const int bid = blockIdx.x;
    const int qblk = bid >> 7;            // 0..3, high bits (XCD slab grouping)
    const int low = bid & 127;
    const int h = low & 15, z = low >> 4;  // z 0..7
    const int b = z >> 1, sp = z & 1;
    const int kvbase = sp * 1024;

    bf16x8 qf[2][2];
#pragma unroll
    for (int qs = 0; qs < 2; qs++) {
        int qrow = b * 512 + qblk * 128 + qs * 64 + wv * 16 + c16;
        qf[qs][0] = *(const bf16x8*)(Qp + (size_t)qrow * 1024 + h * 64 + g * 8);
        qf[qs][1] = *(const bf16x8*)(Qp + (size_t)qrow * 1024 + h * 64 + 32 + g * 8);
    }

    f32x4 acc[2][4] = {};
    float m_s[2] = {-1e30f, -1e30f}, l_s[2] = {0.f, 0.f};   // log2 domain

    const int r0 = tid >> 3, c0 = (tid & 7) ^ (r0 & 7);
    const int r1 = 32 + r0,  c1 = (tid & 7) ^ (r1 & 7);
    const int dst0 = wv * 512, dst1 = 2048 + wv * 512;   // u16 offsets

    auto stageKV = [&](int t) {
        int slot = t % 3;
        int kv0 = kvbase + t * 64;
        u16* dK = &lKV[slot][0][0];
        u16* dV = &lKV[slot][1][0];
        gll16(Kp + (size_t)(b * 2048 + kv0 + r0) * 1024 + h * 64 + c0 * 8, dK + dst0);
        gll16(Kp + (size_t)(b * 2048 + kv0 + r1) * 1024 + h * 64 + c1 * 8, dK + dst1);
        gll16(VpT + (size_t)(h * 64 + r0) * 8192 + b * 2048 + kv0 + c0 * 8, dV + dst0);
        gll16(VpT + (size_t)(h * 64 + r1) * 8192 + b * 2048 + kv0 + c1 * 8, dV + dst1);
    };

    stageKV(0); stageKV(1);
    for (int t = 0; t < NT; ++t) {
        if (t < NT - 1) { WAITV4(); } else { WAITV0(); }
        BAR();
        if (t + 2 < NT) stageKV(t + 2);

        const int slot = t % 3;
        const u16* lK = &lKV[slot][0][0];
        const u16* lV = &lKV[slot][1][0];

        f32x4 s[2][4];
#pragma unroll
        for (int n = 0; n < 4; n++) {
            s[0][n] = f32x4{0.f, 0.f, 0.f, 0.f};
            s[1][n] = f32x4{0.f, 0.f, 0.f, 0.f};
        }
        __builtin_amdgcn_s_setprio(1);
#pragma unroll
        for (int n = 0; n < 4; n++) {
            int key = n * 16 + c16;
#pragma unroll
            for (int kk = 0; kk < 2; kk++) {
                bf16x8 kf = *(const bf16x8*)&lK[key * 64 + (((kk * 4 + g) ^ (key & 7))) * 8];
                s[0][n] = mfma16(kf, qf[0][kk], s[0][n]);
                s[1][n] = mfma16(kf, qf[1][kk], s[1][n]);
            }
        }
        __builtin_amdgcn_s_setprio(0);

        uint32_t r[2][4][2];
#pragma unroll
        for (int qs = 0; qs < 2; qs++) {
            float mn0 = fmaxf(fmaxf(s[qs][0][0], s[qs][0][1]), fmaxf(s[qs][0][2], s[qs][0][3]));
            float mn1 = fmaxf(fmaxf(s[qs][1][0], s[qs][1][1]), fmaxf(s[qs][1][2], s[qs][1][3]));
            float mn2 = fmaxf(fmaxf(s[qs][2][0], s[qs][2][1]), fmaxf(s[qs][2][2], s[qs][2][3]));
            float mn3 = fmaxf(fmaxf(s[qs][3][0], s[qs][3][1]), fmaxf(s[qs][3][2], s[qs][3][3]));
            float mx = fmaxf(fmaxf(mn0, mn1), fmaxf(mn2, mn3));
            mx = fmaxf(mx, __shfl_xor(mx, 16));
            mx = fmaxf(mx, __shfl_xor(mx, 32));

            if (!__all(mx - m_s[qs] <= 8.0f)) {
                float mn = fmaxf(m_s[qs], mx);
                float al = exp2f(m_s[qs] - mn);
                m_s[qs] = mn;
                l_s[qs] *= al;
                float alr[4];
#pragma unroll
                for (int j = 0; j < 4; j++) alr[j] = __shfl(al, g * 4 + j);
#pragma unroll
                for (int nd = 0; nd < 4; nd++)
#pragma unroll
                    for (int j = 0; j < 4; j++) acc[qs][nd][j] *= alr[j];
            }

            float sums[4];
#pragma unroll
            for (int n = 0; n < 4; n++) {
                float p0 = exp2f(s[qs][n][0] - m_s[qs]);
                float p1 = exp2f(s[qs][n][1] - m_s[qs]);
                float p2 = exp2f(s[qs][n][2] - m_s[qs]);
                float p3 = exp2f(s[qs][n][3] - m_s[qs]);
                sums[n] = (p0 + p1) + (p2 + p3);
                union { bf16x2 h; uint32_t u; } ca, cb;
                ca.h[0] = (__bf16)p0; ca.h[1] = (__bf16)p1;
                cb.h[0] = (__bf16)p2; cb.h[1] = (__bf16)p3;
                r[qs][n][0] = ca.u; r[qs][n][1] = cb.u;
            }
            float sum = (sums[0] + sums[1]) + (sums[2] + sums[3]);
            sum += __shfl_xor(sum, 16);
            sum += __shfl_xor(sum, 32);
            l_s[qs] += sum;
        }

        __builtin_amdgcn_s_setprio(1);
#pragma unroll
        for (int kk2 = 0; kk2 < 2; kk2++) {
            union { bf16x8 v8; uint32_t u[4]; } pa0, pa1;
            pa0.u[0] = r[0][kk2 * 2][0];     pa0.u[1] = r[0][kk2 * 2][1];
            pa0.u[2] = r[0][kk2 * 2 + 1][0]; pa0.u[3] = r[0][kk2 * 2 + 1][1];
            pa1.u[0] = r[1][kk2 * 2][0];     pa1.u[1] = r[1][kk2 * 2][1];
            pa1.u[2] = r[1][kk2 * 2 + 1][0]; pa1.u[3] = r[1][kk2 * 2 + 1][1];
#pragma unroll
            for (int nd = 0; nd < 4; nd++) {
                int d = nd * 16 + c16;
                bf16x8 vf = *(const bf16x8*)&lV[d * 64 + (((kk2 * 4 + g) ^ (d & 7))) * 8];
                acc[0][nd] = mfma16(pa0.v8, vf, acc[0][nd]);
                acc[1][nd] = mfma16(pa1.v8, vf, acc[1][nd]);
            }
        }
        __builtin_amdgcn_s_setprio(0);
    }

#pragma unroll
    for (int qs = 0; qs < 2; qs++) {
#pragma unroll
        for (int j = 0; j < 4; j++) {
            int rowq = b * 512 + qblk * 128 + qs * 64 + wv * 16 + g * 4 + j;
            size_t idx = (size_t)sp * 32768 + (size_t)rowq * 16 + h;
#pragma unroll
            for (int nd = 0; nd < 4; nd++)
                Opart[idx * 64 + nd * 16 + c16] = f2bf(acc[qs][nd][j]);
        }
        if (g == 0) {
            int rowq = b * 512 + qblk * 128 + qs * 64 + wv * 16 + c16;
            size_t idx = (size_t)sp * 32768 + (size_t)rowq * 16 + h;
            ml[idx * 2] = m_s[qs];
            ml[idx * 2 + 1] = l_s[qs];
        }
    }
}

// ---------------- combine the 2 kv-split partials -> X bf16 (log2-domain m) ------
__global__ __launch_bounds__(256) void attn_combine_kernel(
        const u16* __restrict__ Opart, const float* __restrict__ ml,
        u16* __restrict__ X) {
    const int tid = threadIdx.x;
    const int r = blockIdx.x * 4 + (tid >> 6);   // rowhead 0..32767
    const int d = tid & 63;
    float m0 = ml[(size_t)r * 2], l0 = ml[(size_t)r * 2 + 1];
    float m1 = ml[(size_t)(32768 + r) * 2], l1 = ml[(size_t)(32768 + r) * 2 + 1];
    float M = fmaxf(m0, m1);
    float a0 = exp2f(m0 - M), a1 = exp2f(m1 - M);
    float li = 1.f / (l0 * a0 + l1 * a1);
    float o0 = bf2f(Opart[(size_t)r * 64 + d]);
    float o1 = bf2f(Opart[(size_t)(32768 + r) * 64 + d]);
    float o = (o0 * a0 + o1 * a1) * li;
    int qrow = r >> 4, h = r & 15;
    X[(size_t)qrow * 1024 + h * 64 + d] = f2bf(o);
}

// ---------------- launch ----------------
extern "C" void kernel_launch(void* const* d_in, const int* in_sizes, int n_in,
                              void* d_out, int out_size, void* d_ws, size_t ws_size,
                              hipStream_t stream) {
    const float* queries = (const float*)d_in[0];   // [4,512,1024]
    const float* context = (const float*)d_in[1];   // [4,2048,1024]
    const float* Wq      = (const float*)d_in[2];   // [1024,1024]
    const float* bq      = (const float*)d_in[3];   // [1024]
    const float* Wkv     = (const float*)d_in[4];   // [1024,2048]
    const float* bkv     = (const float*)d_in[5];   // [2048]
    const float* Wo      = (const float*)d_in[6];   // [1024,1024]
    const float* bo      = (const float*)d_in[7];   // [1024]

    char* ws = (char*)d_ws;
    u16* qb   = (u16*)(ws);                         // queries bf16   4MB (dead after Q-proj)
    u16* cb   = (u16*)(ws + (4ull  << 20));         // context bf16  16MB (dead after KV GEMM)
    u16* WqT  = (u16*)(ws + (20ull << 20));         // Wq^T bf16      2MB
    u16* WkvT = (u16*)(ws + (22ull << 20));         // Wkv^T bf16     4MB
    u16* WoT  = (u16*)(ws + (26ull << 20));         // Wo^T bf16      2MB
    u16* Qp   = (u16*)(ws + (28ull << 20));         // q proj (x0.125*log2e) 4MB
    u16* Kp   = (u16*)(ws + (32ull << 20));         // k proj        16MB
    u16* VpT  = (u16*)(ws + (48ull << 20));         // v proj ^T (vslot cols) 16MB
    u16* X    = (u16*)(ws + (64ull << 20));         // attn out       4MB
    float* ml    = (float*)qb;                      // 512KB, aliases dead qb
    u16*   Opart = (u16*)cb;                        // 8MB bf16 (2 splits), aliases cb

    prep_kernel<<<dim3(14336), dim3(256), 0, stream>>>(queries, context, Wq, Wkv, Wo,
                                                       qb, cb, WqT, WkvT, WoT);

    // fused KV GEMM (blocks 0..255) + Q proj (blocks 256..511)
    // Q scale = 1/8 * log2(e): scores computed directly in exp2 domain
    fused_qkv<<<dim3(512), dim3(512), 0, stream>>>(cb, WkvT, bkv, Kp, VpT,
                                                   qb, WqT, bq, 0.18033688f, Qp);
    attn_split_kernel<<<dim3(512), dim3(256), 0, stream>>>(Qp, Kp, VpT, Opart, ml);
    attn_combine_kernel<<<dim3(8192), dim3(256), 0, stream>>>(Opart, ml, X);
    gemm_bt<2><<<dim3(8, 32), dim3(512), 0, stream>>>(X, WoT, bo, 2048, 1024, 1024,
                                                      1.0f, d_out);
}

// Round 21
// 112.746 us; speedup vs baseline: 1.1066x; 1.0386x over previous
//
#include <hip/hip_runtime.h>
#include <hip/hip_bf16.h>
#include <stdint.h>

typedef unsigned short u16;
typedef __attribute__((ext_vector_type(8))) __bf16 bf16x8;
typedef __attribute__((ext_vector_type(2))) __bf16 bf16x2;
typedef __attribute__((ext_vector_type(4))) float f32x4;
typedef __attribute__((ext_vector_type(4))) u16 u16x4;
typedef __attribute__((ext_vector_type(4))) float f32x4v;

typedef __attribute__((address_space(1))) void gvoid_t;
typedef __attribute__((address_space(3))) void lvoid_t;

#define BAR()    asm volatile("s_barrier" ::: "memory")
#define WAITV0() asm volatile("s_waitcnt vmcnt(0)" ::: "memory")
#define WAITV2() asm volatile("s_waitcnt vmcnt(2)" ::: "memory")
#define WAITV4() asm volatile("s_waitcnt vmcnt(4)" ::: "memory")
#define WAITV8() asm volatile("s_waitcnt vmcnt(8)" ::: "memory")

__device__ inline u16 f2bf(float f) {
    uint32_t u = __float_as_uint(f);
    u += 0x7fff + ((u >> 16) & 1);   // RNE
    return (u16)(u >> 16);
}

__device__ inline float bf2f(u16 v) {
    return __uint_as_float(((uint32_t)v) << 16);
}

__device__ inline void gll16(const void* g, void* l) {
    __builtin_amdgcn_global_load_lds((gvoid_t*)g, (lvoid_t*)l, 16, 0, 0);
}

__device__ inline f32x4 mfma16(bf16x8 a, bf16x8 b, f32x4 c) {
    return __builtin_amdgcn_mfma_f32_16x16x32_bf16(a, b, c, 0, 0, 0);
}

// V slot permutation: context row r (mod 64) -> storage slot, so that the PV
// A-fragment is IN-LANE after swapped QK^T (keys n*16+g*4+j live in lane g).
__device__ inline int vslot(int r) {
    int n = r >> 4;
    return ((n >> 1) << 5) + (((r >> 2) & 3) << 3) + ((n & 1) << 2) + (r & 3);
}

// ---------------- fused prep: casts (blocks 0..10239) + transposes (10240..14335)
__global__ __launch_bounds__(256) void prep_kernel(
        const float* __restrict__ q, const float* __restrict__ c,
        const float* __restrict__ Wq, const float* __restrict__ Wkv,
        const float* __restrict__ Wo, u16* __restrict__ qb,
        u16* __restrict__ cb, u16* __restrict__ WqT,
        u16* __restrict__ WkvT, u16* __restrict__ WoT) {
    const int bid = blockIdx.x;
    const int tid = threadIdx.x;
    if (bid < 10240) {
        int i = bid * 256 + tid;
        const float* src; u16* dst; int j;
        if (i < 524288) { src = q; dst = qb; j = i; }
        else            { src = c; dst = cb; j = i - 524288; }
        f32x4v f = ((const f32x4v*)src)[j];
        u16x4 o;
        o[0] = f2bf(f[0]); o[1] = f2bf(f[1]); o[2] = f2bf(f[2]); o[3] = f2bf(f[3]);
        ((u16x4*)dst)[j] = o;
        return;
    }
    int b2 = bid - 10240;
    const float* W; u16* WT; int N, n0, k0;
    if (b2 < 1024)      { W = Wq;  WT = WqT;  N = 1024; n0 = (b2 & 31) * 32; k0 = (b2 >> 5) * 32; }
    else if (b2 < 3072) { int b3 = b2 - 1024; W = Wkv; WT = WkvT; N = 2048; n0 = (b3 & 63) * 32; k0 = (b3 >> 6) * 32; }
    else                { int b3 = b2 - 3072; W = Wo;  WT = WoT;  N = 1024; n0 = (b3 & 31) * 32; k0 = (b3 >> 5) * 32; }
    __shared__ float t[32][33];
    int x = tid & 31, y = tid >> 5;
    for (int yy = y; yy < 32; yy += 8)
        t[yy][x] = W[(size_t)(k0 + yy) * N + n0 + x];
    __syncthreads();
    for (int yy = y; yy < 32; yy += 8)
        WT[(size_t)(n0 + yy) * 1024 + k0 + x] = f2bf(t[x][yy]);
}

// ---------------- small GEMM: 64x128 tile, 8 waves, 4-slot counted ring ---------
// (R12-proven; used standalone for the O projection, MODE 2)
template <int MODE>
__global__ __launch_bounds__(512, 2) void gemm_bt(
        const u16* __restrict__ A, const u16* __restrict__ Bt,
        const float* __restrict__ bias, int M, int N, int K,
        float scale, void* __restrict__ out0) {
    __shared__ u16 lds[4][6144];          // [slot][A: 64*32 | B at +2048: 128*32]
    const int NT = K >> 5;                // K/32
    const int tid = threadIdx.x;          // 0..511
    const int lane = tid & 63, wv = tid >> 6;   // wv 0..7
    const int c16 = lane & 15, g = lane >> 4;
    const int m0 = blockIdx.y * 64, n0 = blockIdx.x * 128;

    const int idxA = (wv & 3) * 64 + lane;
    const int rA = idxA >> 2, ccA = (idxA & 3) ^ ((rA >> 1) & 3);
    const size_t offA = (size_t)(m0 + rA) * K + ccA * 8;
    const int dstA = (wv & 3) * 512;
    const int idxB = wv * 64 + lane;
    const int rB = idxB >> 2, ccB = (idxB & 3) ^ ((rB >> 1) & 3);
    const size_t offB = (size_t)(n0 + rB) * K + ccB * 8;
    const int dstB = 2048 + wv * 512;

    auto stage = [&](int t) {
        gll16(A + offA + t * 32, &lds[t & 3][dstA]);
        gll16(Bt + offB + t * 32, &lds[t & 3][dstB]);
    };

    const int wm = (wv >> 1) * 16, wn = (wv & 1) * 64;
    f32x4 acc[4] = {};

    auto compute = [&](int slot) {
        const u16* la = &lds[slot][0];
        const u16* lb = &lds[slot][2048];
        int rowa = wm + c16;
        bf16x8 af = *(const bf16x8*)&la[rowa * 32 + (g ^ ((rowa >> 1) & 3)) * 8];
        bf16x8 bfr[4];
#pragma unroll
        for (int n = 0; n < 4; n++) {
            int row = wn + n * 16 + c16;
            bfr[n] = *(const bf16x8*)&lb[row * 32 + (g ^ ((row >> 1) & 3)) * 8];
        }
#pragma unroll
        for (int n = 0; n < 4; n++)
            acc[n] = mfma16(af, bfr[n], acc[n]);
    };

    stage(0); stage(1); stage(2);        // 6 loads/thread in flight

    for (int t = 0; t < NT - 2; ++t) {
        WAITV4();
        BAR();
        if (t + 3 < NT) stage(t + 3);
        compute(t & 3);
    }
    WAITV2(); BAR(); compute((NT - 2) & 3);
    WAITV0(); BAR(); compute((NT - 1) & 3);

#pragma unroll
    for (int n = 0; n < 4; n++) {
        int col = n0 + wn + n * 16 + c16;
        float bv = bias[col];
        int rowb = m0 + wm + g * 4;
#pragma unroll
        for (int j = 0; j < 4; j++) {
            float v = (acc[n][j] + bv) * scale;
            int row = rowb + j;
            if (MODE == 0) {
                ((u16*)out0)[(size_t)row * N + col] = f2bf(v);
            } else {
                ((float*)out0)[(size_t)row * N + col] = v;
            }
        }
    }
}

// ---------------- fused QKV projection dispatch --------------------------------
// (R15/R20-proven) Blocks 0..255: KV GEMM 256x256 4-slot counted ring.
// Blocks 256..511: Q projection 64x128 ring, 49KB view of the same 128KB LDS.
__global__ __launch_bounds__(512, 2) void fused_qkv(
        const u16* __restrict__ cb, const u16* __restrict__ WkvT,
        const float* __restrict__ bkv, u16* __restrict__ Kp,
        u16* __restrict__ VpT,
        const u16* __restrict__ qb, const u16* __restrict__ WqT,
        const float* __restrict__ bq, float qscale, u16* __restrict__ Qp) {
    __shared__ u16 smem[4][2][8192];      // 131072 B
    const int tid = threadIdx.x;
    const int lane = tid & 63, wv = tid >> 6;
    const int c16 = lane & 15, g = lane >> 4;
    const int bidg = blockIdx.x;

    if (bidg < 256) {
        const int K = 1024, NT = 32;
        const int cpx = 32;
        const int sw = (bidg & 7) * cpx + (bidg >> 3);
        const int bx = sw & 7, by = sw >> 3;
        const int m0 = by * 256, n0 = bx * 256;

        const int isB = wv >> 2;
        const int rbase = (wv & 3) * 64;
        const u16* src = isB ? WkvT : cb;
        const int base0 = isB ? n0 : m0;
        size_t off[4];
        const u16* ldst[4];
#pragma unroll
        for (int i = 0; i < 4; i++) {
            int rl = rbase + i * 16 + (lane >> 2);
            int ch = (lane & 3) ^ ((rl >> 1) & 3);
            off[i] = (size_t)(base0 + rl) * K + ch * 8;
            ldst[i] = &smem[0][0][0] + ((size_t)isB * 256 * 32) + (size_t)(rbase + i * 16) * 32;
        }
        const size_t slotStride = 2 * 256 * 32;

        auto stage = [&](int t) {
            const u16* s0 = src + (size_t)t * 32;
            u16* d = (u16*)ldst[0] + (size_t)(t & 3) * slotStride;
            gll16(s0 + off[0], d);
            gll16(s0 + off[1], d + 16 * 32);
            gll16(s0 + off[2], d + 32 * 32);
            gll16(s0 + off[3], d + 48 * 32);
        };

        const int wm = wv >> 2;
        const int wn = wv & 3;
        f32x4 acc[8][4] = {};

        auto compute = [&](int slot) {
            const u16* la = &smem[slot][0][0];
            const u16* lb = &smem[slot][1][0];
            bf16x8 af[8], bfr[4];
#pragma unroll
            for (int m = 0; m < 8; m++) {
                int row = wm * 128 + m * 16 + c16;
                af[m] = *(const bf16x8*)&la[row * 32 + (g ^ ((row >> 1) & 3)) * 8];
            }
#pragma unroll
            for (int n = 0; n < 4; n++) {
                int row = wn * 64 + n * 16 + c16;
                bfr[n] = *(const bf16x8*)&lb[row * 32 + (g ^ ((row >> 1) & 3)) * 8];
            }
#pragma unroll
            for (int m = 0; m < 8; m++)
#pragma unroll
                for (int n = 0; n < 4; n++)
                    acc[m][n] = mfma16(af[m], bfr[n], acc[m][n]);
        };

        stage(0); stage(1); stage(2);

        for (int t = 0; t < NT - 2; ++t) {
            WAITV8();
            BAR();
            if (t + 3 < NT) stage(t + 3);
            compute(t & 3);
        }
        WAITV4(); BAR(); compute((NT - 2) & 3);
        WAITV0(); BAR(); compute((NT - 1) & 3);

        const bool isV = (n0 >= 1024);
#pragma unroll
        for (int n = 0; n < 4; n++) {
            int col = n0 + wn * 64 + n * 16 + c16;
            float bv = bkv[col];
#pragma unroll
            for (int m = 0; m < 8; m++) {
                int rowb = m0 + wm * 128 + m * 16 + g * 4;
                if (isV) {
                    u16x4 pk;
#pragma unroll
                    for (int j = 0; j < 4; j++) pk[j] = f2bf(acc[m][n][j] + bv);
                    int vcol = (rowb & ~63) + vslot(rowb & 63);
                    *(u16x4*)&VpT[(size_t)(col - 1024) * 8192 + vcol] = pk;
                } else {
#pragma unroll
                    for (int j = 0; j < 4; j++)
                        Kp[(size_t)(rowb + j) * 1024 + col] = f2bf(acc[m][n][j] + bv);
                }
            }
        }
    } else {
        const int K = 1024, N = 1024, NT = 32;
        const int b2 = bidg - 256;
        const int m0 = (b2 >> 3) * 64, n0 = (b2 & 7) * 128;
        u16* base = &smem[0][0][0];       // Q path uses first 24576 u16 (49KB)

        const int idxA = (wv & 3) * 64 + lane;
        const int rA = idxA >> 2, ccA = (idxA & 3) ^ ((rA >> 1) & 3);
        const size_t offA = (size_t)(m0 + rA) * K + ccA * 8;
        const int dstA = (wv & 3) * 512;
        const int idxB = wv * 64 + lane;
        const int rB = idxB >> 2, ccB = (idxB & 3) ^ ((rB >> 1) & 3);
        const size_t offB = (size_t)(n0 + rB) * K + ccB * 8;
        const int dstB = 2048 + wv * 512;

        auto stage = [&](int t) {
            u16* d = base + (t & 3) * 6144;
            gll16(qb + offA + t * 32, d + dstA);
            gll16(WqT + offB + t * 32, d + dstB);
        };

        const int wm = (wv >> 1) * 16, wn = (wv & 1) * 64;
        f32x4 acc[4] = {};

        auto compute = [&](int slot) {
            const u16* la = base + slot * 6144;
            const u16* lb = la + 2048;
            int rowa = wm + c16;
            bf16x8 af = *(const bf16x8*)&la[rowa * 32 + (g ^ ((rowa >> 1) & 3)) * 8];
            bf16x8 bfr[4];
#pragma unroll
            for (int n = 0; n < 4; n++) {
                int row = wn + n * 16 + c16;
                bfr[n] = *(const bf16x8*)&lb[row * 32 + (g ^ ((row >> 1) & 3)) * 8];
            }
#pragma unroll
            for (int n = 0; n < 4; n++)
                acc[n] = mfma16(af, bfr[n], acc[n]);
        };

        stage(0); stage(1); stage(2);

        for (int t = 0; t < NT - 2; ++t) {
            WAITV4();
            BAR();
            if (t + 3 < NT) stage(t + 3);
            compute(t & 3);
        }
        WAITV2(); BAR(); compute((NT - 2) & 3);
        WAITV0(); BAR(); compute((NT - 1) & 3);

#pragma unroll
        for (int n = 0; n < 4; n++) {
            int col = n0 + wn + n * 16 + c16;
            float bv = bq[col];
            int rowb = m0 + wm + g * 4;
#pragma unroll
            for (int j = 0; j < 4; j++) {
                float v = (acc[n][j] + bv) * qscale;
                Qp[(size_t)(rowb + j) * N + col] = f2bf(v);
            }
        }
    }
}

// ---------------- flash attention: INTRA-BLOCK kv-split, fused merge -----------
// grid 256 (qblk high bits -> XCD slab grouping), 512 threads = 8 waves.
// Waves 0-3: keys 0..1023; waves 4-7: keys 1024..2047; both halves own the same
// 128 q-rows (4 waves x 2 q-sets x 16). Per half: R6-proven 2-slot ring (stage
// after BAR, WAITV0 at top - loads cover under the long compute). LDS = 2 slots
// x 2 halves x (K,V) x 8KB = 64KB -> 2 blocks/CU (16 waves/CU, up from 12).
// Tail: half-1 writes fp32 partial O + m/l into the dead staging LDS; barrier;
// half-0 merges in registers and writes X directly (combine dispatch gone,
// Opart/ml HBM round-trip gone; all sync intra-block).
__global__ __launch_bounds__(512, 2) void attn_kernel(
        const u16* __restrict__ Qp, const u16* __restrict__ Kp,
        const u16* __restrict__ VpT, u16* __restrict__ X) {
    __shared__ u16 lKV[2][2][2][4096];   // [slot][half][K=0/V=1][64*64] = 65536 B
    const int NT = 16;
    const int tid = threadIdx.x;
    const int lane = tid & 63, wv = tid >> 6;      // wv 0..7
    const int wvl = wv & 3, sp = wv >> 2;
    const int c16 = lane & 15, g = lane >> 4;
    const int bid = blockIdx.x;
    const int qblk = bid >> 6;            // 0..3 high bits (XCD slab grouping)
    const int low = bid & 63;
    const int h = low & 15, b = low >> 4;
    const int kvbase = sp * 1024;

    bf16x8 qf[2][2];
#pragma unroll
    for (int qs = 0; qs < 2; qs++) {
        int qrow = b * 512 + qblk * 128 + qs * 64 + wvl * 16 + c16;
        qf[qs][0] = *(const bf16x8*)(Qp + (size_t)qrow * 1024 + h * 64 + g * 8);
        qf[qs][1] = *(const bf16x8*)(Qp + (size_t)qrow * 1024 + h * 64 + 32 + g * 8);
    }

    f32x4 acc[2][4] = {};
    float m_s[2] = {-1e30f, -1e30f}, l_s[2] = {0.f, 0.f};   // log2 domain

    // staging within half: local thread tl = tid & 255 covers rows r0, r0+32
    const int tl = tid & 255;
    const int r0 = tl >> 3, c0 = (tl & 7) ^ (r0 & 7);
    const int r1 = 32 + r0,  c1 = (tl & 7) ^ (r1 & 7);
    const int dst0 = wvl * 512, dst1 = 2048 + wvl * 512;   // u16 offsets in region

    auto stageKV = [&](int slot, int t) {
        int kv0 = kvbase + t * 64;
        u16* dK = &lKV[slot][sp][0][0];
        u16* dV = &lKV[slot][sp][1][0];
        gll16(Kp + (size_t)(b * 2048 + kv0 + r0) * 1024 + h * 64 + c0 * 8, dK + dst0);
        gll16(Kp + (size_t)(b * 2048 + kv0 + r1) * 1024 + h * 64 + c1 * 8, dK + dst1);
        gll16(VpT + (size_t)(h * 64 + r0) * 8192 + b * 2048 + kv0 + c0 * 8, dV + dst0);
        gll16(VpT + (size_t)(h * 64 + r1) * 8192 + b * 2048 + kv0 + c1 * 8, dV + dst1);
    };

    stageKV(0, 0);
    for (int t = 0; t < NT; ++t) {
        WAITV0();                          // tile t landed (covered by compute t-1)
        BAR();
        if (t + 1 < NT) stageKV((t + 1) & 1, t + 1);   // slot free: compute(t-1) done

        const int slot = t & 1;
        const u16* lK = &lKV[slot][sp][0][0];
        const u16* lV = &lKV[slot][sp][1][0];

        f32x4 s[2][4];
#pragma unroll
        for (int n = 0; n < 4; n++) {
            s[0][n] = f32x4{0.f, 0.f, 0.f, 0.f};
            s[1][n] = f32x4{0.f, 0.f, 0.f, 0.f};
        }
        __builtin_amdgcn_s_setprio(1);
#pragma unroll
        for (int n = 0; n < 4; n++) {
            int key = n * 16 + c16;
#pragma unroll
            for (int kk = 0; kk < 2; kk++) {
                bf16x8 kf = *(const bf16x8*)&lK[key * 64 + (((kk * 4 + g) ^ (key & 7))) * 8];
                s[0][n] = mfma16(kf, qf[0][kk], s[0][n]);
                s[1][n] = mfma16(kf, qf[1][kk], s[1][n]);
            }
        }
        __builtin_amdgcn_s_setprio(0);

        uint32_t r[2][4][2];
#pragma unroll
        for (int qs = 0; qs < 2; qs++) {
            float mn0 = fmaxf(fmaxf(s[qs][0][0], s[qs][0][1]), fmaxf(s[qs][0][2], s[qs][0][3]));
            float mn1 = fmaxf(fmaxf(s[qs][1][0], s[qs][1][1]), fmaxf(s[qs][1][2], s[qs][1][3]));
            float mn2 = fmaxf(fmaxf(s[qs][2][0], s[qs][2][1]), fmaxf(s[qs][2][2], s[qs][2][3]));
            float mn3 = fmaxf(fmaxf(s[qs][3][0], s[qs][3][1]), fmaxf(s[qs][3][2], s[qs][3][3]));
            float mx = fmaxf(fmaxf(mn0, mn1), fmaxf(mn2, mn3));
            mx = fmaxf(mx, __shfl_xor(mx, 16));
            mx = fmaxf(mx, __shfl_xor(mx, 32));

            if (!__all(mx - m_s[qs] <= 8.0f)) {
                float mn = fmaxf(m_s[qs], mx);
                float al = exp2f(m_s[qs] - mn);
                m_s[qs] = mn;
                l_s[qs] *= al;
                float alr[4];
#pragma unroll
                for (int j = 0; j < 4; j++) alr[j] = __shfl(al, g * 4 + j);
#pragma unroll
                for (int nd = 0; nd < 4; nd++)
#pragma unroll
                    for (int j = 0; j < 4; j++) acc[qs][nd][j] *= alr[j];
            }

            float sums[4];
#pragma unroll
            for (int n = 0; n < 4; n++) {
                float p0 = exp2f(s[qs][n][0] - m_s[qs]);
                float p1 = exp2f(s[qs][n][1] - m_s[qs]);
                float p2 = exp2f(s[qs][n][2] - m_s[qs]);
                float p3 = exp2f(s[qs][n][3] - m_s[qs]);
                sums[n] = (p0 + p1) + (p2 + p3);
                union { bf16x2 hh; uint32_t u; } ca, cb2;
                ca.hh[0] = (__bf16)p0; ca.hh[1] = (__bf16)p1;
                cb2.hh[0] = (__bf16)p2; cb2.hh[1] = (__bf16)p3;
                r[qs][n][0] = ca.u; r[qs][n][1] = cb2.u;
            }
            float sum = (sums[0] + sums[1]) + (sums[2] + sums[3]);
            sum += __shfl_xor(sum, 16);
            sum += __shfl_xor(sum, 32);
            l_s[qs] += sum;
        }

        __builtin_amdgcn_s_setprio(1);
#pragma unroll
        for (int kk2 = 0; kk2 < 2; kk2++) {
            union { bf16x8 v8; uint32_t u[4]; } pa0, pa1;
            pa0.u[0] = r[0][kk2 * 2][0];     pa0.u[1] = r[0][kk2 * 2][1];
            pa0.u[2] = r[0][kk2 * 2 + 1][0]; pa0.u[3] = r[0][kk2 * 2 + 1][1];
            pa1.u[0] = r[1][kk2 * 2][0];     pa1.u[1] = r[1][kk2 * 2][1];
            pa1.u[2] = r[1][kk2 * 2 + 1][0]; pa1.u[3] = r[1][kk2 * 2 + 1][1];
#pragma unroll
            for (int nd = 0; nd < 4; nd++) {
                int d = nd * 16 + c16;
                bf16x8 vf = *(const bf16x8*)&lV[d * 64 + (((kk2 * 4 + g) ^ (d & 7))) * 8];
                acc[0][nd] = mfma16(pa0.v8, vf, acc[0][nd]);
                acc[1][nd] = mfma16(pa1.v8, vf, acc[1][nd]);
            }
        }
        __builtin_amdgcn_s_setprio(0);
    }

    // ---- intra-block merge: half 1 -> LDS (fp32), half 0 merges + writes X ----
    __syncthreads();                      // all waves done reading staging LDS
    float* fb = (float*)&lKV[0][0][0][0]; // 33KB merge buffer: O[128][64] + ml[128][2]
    if (sp == 1) {
#pragma unroll
        for (int qs = 0; qs < 2; qs++) {
#pragma unroll
            for (int j = 0; j < 4; j++) {
                int rloc = qs * 64 + wvl * 16 + g * 4 + j;
#pragma unroll
                for (int nd = 0; nd < 4; nd++)
                    fb[rloc * 64 + nd * 16 + c16] = acc[qs][nd][j];
            }
            if (g == 0) {
                int rloc = qs * 64 + wvl * 16 + c16;
                fb[8192 + rloc * 2]     = m_s[qs];
                fb[8192 + rloc * 2 + 1] = l_s[qs];
            }
        }
    }
    __syncthreads();
    if (sp == 0) {
#pragma unroll
        for (int qs = 0; qs < 2; qs++) {
            float mo[4], lo[4];
#pragma unroll
            for (int j = 0; j < 4; j++) {
                mo[j] = __shfl(m_s[qs], g * 4 + j);
                lo[j] = __shfl(l_s[qs], g * 4 + j);
            }
#pragma unroll
            for (int j = 0; j < 4; j++) {
                int rloc = qs * 64 + wvl * 16 + g * 4 + j;
                float m1 = fb[8192 + rloc * 2], l1 = fb[8192 + rloc * 2 + 1];
                float M = fmaxf(mo[j], m1);
                float a0 = exp2f(mo[j] - M), a1 = exp2f(m1 - M);
                float li = 1.f / (lo[j] * a0 + l1 * a1);
                int rowq = b * 512 + qblk * 128 + rloc;
#pragma unroll
                for (int nd = 0; nd < 4; nd++) {
                    float o1 = fb[rloc * 64 + nd * 16 + c16];
                    float o = (acc[qs][nd][j] * a0 + o1 * a1) * li;
                    X[(size_t)rowq * 1024 + h * 64 + nd * 16 + c16] = f2bf(o);
                }
            }
        }
    }
}

// ---------------- launch ----------------
extern "C" void kernel_launch(void* const* d_in, const int* in_sizes, int n_in,
                              void* d_out, int out_size, void* d_ws, size_t ws_size,
                              hipStream_t stream) {
    const float* queries = (const float*)d_in[0];   // [4,512,1024]
    const float* context = (const float*)d_in[1];   // [4,2048,1024]
    const float* Wq      = (const float*)d_in[2];   // [1024,1024]
    const float* bq      = (const float*)d_in[3];   // [1024]
    const float* Wkv     = (const float*)d_in[4];   // [1024,2048]
    const float* bkv     = (const float*)d_in[5];   // [2048]
    const float* Wo      = (const float*)d_in[6];   // [1024,1024]
    const float* bo      = (const float*)d_in[7];   // [1024]

    char* ws = (char*)d_ws;
    u16* qb   = (u16*)(ws);                         // queries bf16   4MB (dead after Q-proj)
    u16* cb   = (u16*)(ws + (4ull  << 20));         // context bf16  16MB (dead after KV GEMM)
    u16* WqT  = (u16*)(ws + (20ull << 20));         // Wq^T bf16      2MB
    u16* WkvT = (u16*)(ws + (22ull << 20));         // Wkv^T bf16     4MB
    u16* WoT  = (u16*)(ws + (26ull << 20));         // Wo^T bf16      2MB
    u16* Qp   = (u16*)(ws + (28ull << 20));         // q proj (x0.125*log2e) 4MB
    u16* Kp   = (u16*)(ws + (32ull << 20));         // k proj        16MB
    u16* VpT  = (u16*)(ws + (48ull << 20));         // v proj ^T (vslot cols) 16MB
    u16* X    = (u16*)(ws + (64ull << 20));         // attn out       4MB

    prep_kernel<<<dim3(14336), dim3(256), 0, stream>>>(queries, context, Wq, Wkv, Wo,
                                                       qb, cb, WqT, WkvT, WoT);

    // fused KV GEMM (blocks 0..255) + Q proj (blocks 256..511)
    // Q scale = 1/8 * log2(e): scores computed directly in exp2 domain
    fused_qkv<<<dim3(512), dim3(512), 0, stream>>>(cb, WkvT, bkv, Kp, VpT,
                                                   qb, WqT, bq, 0.18033688f, Qp);
    attn_kernel<<<dim3(256), dim3(512), 0, stream>>>(Qp, Kp, VpT, X);
    gemm_bt<2><<<dim3(8, 32), dim3(512), 0, stream>>>(X, WoT, bo, 2048, 1024, 1024,
                                                      1.0f, d_out);
}